// Round 4
// baseline (581.518 us; speedup 1.0000x reference)
//
#include <hip/hip_runtime.h>
#include <stdint.h>

typedef unsigned short u16;
typedef unsigned int u32;
typedef __attribute__((ext_vector_type(8))) short s16x8;
typedef __attribute__((ext_vector_type(8))) __bf16 bf16x8;
typedef __attribute__((ext_vector_type(4))) float f32x4;
typedef __attribute__((ext_vector_type(4))) u32 u32x4;
typedef __attribute__((ext_vector_type(4))) u16 u16x4;

#define L_TOT 32768

__device__ __forceinline__ u32 f2bf(float f){
  u32 u = __builtin_bit_cast(u32, f);
  return (u + 0x7FFFu + ((u >> 16) & 1u)) >> 16;
}

__device__ __forceinline__ f32x4 mfma16(s16x8 a, s16x8 b, f32x4 c){
  return __builtin_amdgcn_mfma_f32_16x16x32_bf16(
      __builtin_bit_cast(bf16x8, a), __builtin_bit_cast(bf16x8, b), c, 0, 0, 0);
}

__device__ __forceinline__ void gload16(const void* g, void* l){
  __builtin_amdgcn_global_load_lds(
      (const __attribute__((address_space(1))) void*)g,
      (__attribute__((address_space(3))) void*)l, 16, 0, 0);
}

__device__ __forceinline__ u32 cvtpk(float lo, float hi){
  u32 r;
  asm("v_cvt_pk_bf16_f32 %0, %1, %2" : "=v"(r) : "v"(lo), "v"(hi));
  return r;
}

// sum across the 16 lanes of each row-group, VALU-only
__device__ __forceinline__ float dpp_reduce16(float x){
  float y;
  asm("v_add_f32_dpp %0, %1, %1 row_ror:8 row_mask:0xf bank_mask:0xf"
      : "=&v"(y) : "v"(x));
  asm("v_add_f32_dpp %0, %1, %1 row_ror:4 row_mask:0xf bank_mask:0xf"
      : "=&v"(x) : "v"(y));
  asm("v_add_f32_dpp %0, %1, %1 quad_perm:[2,3,0,1] row_mask:0xf bank_mask:0xf"
      : "=&v"(y) : "v"(x));
  asm("v_add_f32_dpp %0, %1, %1 quad_perm:[1,0,3,2] row_mask:0xf bank_mask:0xf"
      : "=&v"(x) : "v"(y));
  return x;
}

// C-frag (rows l=mt*16+g*4+j at col=l15) of two tiles -> A/B-frag (k=l in g*8+e, m/n at l15)
// R0..R3 built via: pl32: D.hi<->S.lo ; pl16: D.odd16rows<->S.even16rows
__device__ __forceinline__ s16x8 build_frag(f32x4 t0, f32x4 t1){
  u32 p0 = cvtpk(t0.x, t0.y);   // tile0 rows j0,j1
  u32 p1 = cvtpk(t0.z, t0.w);   // tile0 rows j2,j3
  u32 p2 = cvtpk(t1.x, t1.y);   // tile1 rows j0,j1
  u32 p3 = cvtpk(t1.z, t1.w);   // tile1 rows j2,j3
  asm("v_permlane32_swap_b32 %0, %1" : "+v"(p0), "+v"(p2));
  asm("v_permlane16_swap_b32 %0, %1" : "+v"(p0), "+v"(p2));
  asm("v_permlane32_swap_b32 %0, %1" : "+v"(p1), "+v"(p3));
  asm("v_permlane16_swap_b32 %0, %1" : "+v"(p1), "+v"(p3));
  u32x4 r; r.x = p0; r.y = p1; r.z = p2; r.w = p3;
  return __builtin_bit_cast(s16x8, r);
}

// center+scale (LayerNorm without gamma/beta): acc <- rstd*(acc+bias-mean)
__device__ __forceinline__ void ln_center(f32x4 (&acc)[2][8], const float (&br)[8]){
  #pragma unroll
  for (int mt = 0; mt < 2; ++mt){
    f32x4 sum = {0.f,0.f,0.f,0.f}, sq = {0.f,0.f,0.f,0.f};
    #pragma unroll
    for (int nt = 0; nt < 8; ++nt){
      f32x4 t = acc[mt][nt] + f32x4{br[nt], br[nt], br[nt], br[nt]};
      acc[mt][nt] = t; sum += t; sq += t * t;
    }
    f32x4 s4, ns4;
    #pragma unroll
    for (int j = 0; j < 4; ++j){
      float ss = dpp_reduce16(sum[j]);
      float qq = dpp_reduce16(sq[j]);
      float mean = ss * 0.0078125f;
      float var  = qq * 0.0078125f - mean * mean;
      float rstd = rsqrtf(var + 1e-5f);
      s4[j] = rstd; ns4[j] = -mean * rstd;
    }
    #pragma unroll
    for (int nt = 0; nt < 8; ++nt) acc[mt][nt] = acc[mt][nt] * s4 + ns4;
  }
}

// ------- prep: v -> bf16 X; Wk/Wv -> bf16 in MFMA B-fragment order -------
__global__ void kprep(const float* __restrict__ v, const float* __restrict__ Wk,
                      const float* __restrict__ Wv, u16* __restrict__ X,
                      u16* __restrict__ WkF, u16* __restrict__ WvF){
  int tid = blockIdx.x * blockDim.x + threadIdx.x;
  int stride = gridDim.x * blockDim.x;
  for (int i = tid; i < 2097152; i += stride){
    float4 f = *((const float4*)v + i);
    u16x4 o; o.x = (u16)f2bf(f.x); o.y = (u16)f2bf(f.y); o.z = (u16)f2bf(f.z); o.w = (u16)f2bf(f.w);
    *((u16x4*)X + i) = o;
  }
  for (int i = tid; i < 131072; i += stride){
    int e = i & 7, ln = (i >> 3) & 63, ks = (i >> 9) & 3, nt = (i >> 11) & 7, h = i >> 14;
    int c = ks * 32 + (ln >> 4) * 8 + e;
    int n = nt * 16 + (ln & 15);
    int src = c * 1024 + h * 128 + n;
    WkF[i] = (u16)f2bf(Wk[src]);
    WvF[i] = (u16)f2bf(Wv[src]);
  }
}

// --- fused proj+LN+G, barrier-free: each wave owns 512 rows, full G in regs ---
__global__ __launch_bounds__(256, 1) void kattn(
    const u16* __restrict__ X, const u16* __restrict__ WkF, const u16* __restrict__ WvF,
    const float* __restrict__ bk, const float* __restrict__ bv,
    float* __restrict__ G, float* __restrict__ KBar, float* __restrict__ VBar)
{
  __shared__ char sW[65536];   // WkF frags | WvF frags
  const int tid = threadIdx.x;
  const int wid = tid >> 6, lane = tid & 63, g = lane >> 4, l15 = lane & 15;
  const int bh = blockIdx.x >> 4, lgrp = blockIdx.x & 15;
  const int b = bh >> 3, h = bh & 7;

  {
    const char* gwk = (const char*)(WkF + h * 16384);
    const char* gwv = (const char*)(WvF + h * 16384);
    #pragma unroll
    for (int c = 0; c < 8; ++c){
      u32 o = (u32)(c * 4096 + tid * 16);
      gload16(gwk + o, sW + o);
      gload16(gwv + o, sW + 32768 + o);
    }
  }
  float brk[8], brv[8];
  #pragma unroll
  for (int nt = 0; nt < 8; ++nt){
    brk[nt] = bk[h * 128 + nt * 16 + l15];
    brv[nt] = bv[h * 128 + nt * 16 + l15];
  }
  asm volatile("s_waitcnt vmcnt(0)" ::: "memory");
  __builtin_amdgcn_s_barrier();

  f32x4 gacc[8][8];
  #pragma unroll
  for (int p = 0; p < 8; ++p)
    #pragma unroll
    for (int q = 0; q < 8; ++q) gacc[p][q] = f32x4{0.f,0.f,0.f,0.f};
  float kb[8] = {0,0,0,0,0,0,0,0}, vb[8] = {0,0,0,0,0,0,0,0};

  // this wave's rows: lgrp*2048 + wid*512 + it*32 + mt*16 + l15
  const char* xbase = (const char*)(X + (size_t)b * (L_TOT * 128))
                    + (size_t)(lgrp * 2048 + wid * 512 + l15) * 256 + g * 16;
  const u32 wread = (u32)(lane * 16);

#define PREF(dst, it) { \
  const char* p_ = xbase + (size_t)(it) * 8192; \
  _Pragma("unroll") for (int mt_ = 0; mt_ < 2; ++mt_) \
  _Pragma("unroll") for (int ks_ = 0; ks_ < 4; ++ks_) \
    dst[mt_][ks_] = *(const s16x8*)(p_ + mt_ * 4096 + ks_ * 64); }

#define STEP(F, FN, itn) { \
    f32x4 acc[2][8]; \
    s16x8 afr[8], bfr[8]; \
    /* K proj */ \
    _Pragma("unroll") for (int mt = 0; mt < 2; ++mt) \
      _Pragma("unroll") for (int nt = 0; nt < 8; ++nt) acc[mt][nt] = f32x4{0.f,0.f,0.f,0.f}; \
    _Pragma("unroll") for (int ks = 0; ks < 4; ++ks) \
      _Pragma("unroll") for (int nt = 0; nt < 8; ++nt){ \
        s16x8 wf = *(const s16x8*)(sW + wread + (nt * 4 + ks) * 1024); \
        acc[0][nt] = mfma16(F[0][ks], wf, acc[0][nt]); \
        acc[1][nt] = mfma16(F[1][ks], wf, acc[1][nt]); \
      } \
    ln_center(acc, brk); \
    _Pragma("unroll") for (int nt = 0; nt < 8; ++nt){ \
      f32x4 s_ = acc[0][nt] + acc[1][nt]; \
      kb[nt] += (s_.x + s_.y) + (s_.z + s_.w); \
      afr[nt] = build_frag(acc[0][nt], acc[1][nt]); \
    } \
    /* V proj */ \
    _Pragma("unroll") for (int mt = 0; mt < 2; ++mt) \
      _Pragma("unroll") for (int nt = 0; nt < 8; ++nt) acc[mt][nt] = f32x4{0.f,0.f,0.f,0.f}; \
    _Pragma("unroll") for (int ks = 0; ks < 4; ++ks) \
      _Pragma("unroll") for (int nt = 0; nt < 8; ++nt){ \
        s16x8 wf = *(const s16x8*)(sW + 32768 + wread + (nt * 4 + ks) * 1024); \
        acc[0][nt] = mfma16(F[0][ks], wf, acc[0][nt]); \
        acc[1][nt] = mfma16(F[1][ks], wf, acc[1][nt]); \
      } \
    ln_center(acc, brv); \
    _Pragma("unroll") for (int nt = 0; nt < 8; ++nt){ \
      f32x4 s_ = acc[0][nt] + acc[1][nt]; \
      vb[nt] += (s_.x + s_.y) + (s_.z + s_.w); \
      bfr[nt] = build_frag(acc[0][nt], acc[1][nt]); \
    } \
    /* prefetch next rows while G runs */ \
    PREF(FN, itn); \
    /* G += K''^T V'' */ \
    _Pragma("unroll") for (int p = 0; p < 8; ++p) \
      _Pragma("unroll") for (int q = 0; q < 8; ++q) \
        gacc[p][q] = mfma16(afr[p], bfr[q], gacc[p][q]); \
  }

  s16x8 af[2][4], afn[2][4];
  PREF(af, 0);
  #pragma unroll 1
  for (int it2 = 0; it2 < 16; it2 += 2){
    STEP(af, afn, it2 + 1);
    STEP(afn, af, (it2 + 2 < 16) ? (it2 + 2) : 0);
  }
#undef STEP
#undef PREF

  float* Gbh = G + (size_t)bh * 16384;
  #pragma unroll
  for (int p = 0; p < 8; ++p)
    #pragma unroll
    for (int q = 0; q < 8; ++q)
      #pragma unroll
      for (int j = 0; j < 4; ++j)
        atomicAdd(Gbh + (p * 16 + g * 4 + j) * 128 + q * 16 + l15, gacc[p][q][j]);

  #pragma unroll
  for (int nt = 0; nt < 8; ++nt){
    float s = kb[nt];
    s += __shfl_xor(s, 16); s += __shfl_xor(s, 32);
    if (g == 0) atomicAdd(KBar + bh * 128 + nt * 16 + l15, s);
    float t = vb[nt];
    t += __shfl_xor(t, 16); t += __shfl_xor(t, 32);
    if (g == 0) atomicAdd(VBar + bh * 128 + nt * 16 + l15, t);
  }
}

// --------- fold: AM = corrections(G); tmp = AM@Wo ; W4 += Wq@tmp/n ; c4 ---------
__global__ __launch_bounds__(256) void kfold(
    const float* __restrict__ G, const float* __restrict__ KBar, const float* __restrict__ VBar,
    const float* __restrict__ gk, const float* __restrict__ bbk,
    const float* __restrict__ gv, const float* __restrict__ bbv,
    const float* __restrict__ Wo, const float* __restrict__ Wq,
    const float* __restrict__ Wq_b, const float* __restrict__ Wo_b,
    float* __restrict__ W4, float* __restrict__ c4)
{
  extern __shared__ float fsm[];
  float* sA = fsm;               // [128][129]
  float* sS = fsm + 128 * 129;   // [128][33]
  int blk = blockIdx.x;
  int bh = blk >> 2, eq = blk & 3;
  int b = bh >> 3, hs = bh & 7;
  int tid = threadIdx.x;

  const float* gkh = gk + hs * 128; const float* bkh = bbk + hs * 128;
  const float* gvh = gv + hs * 128; const float* bvh = bbv + hs * 128;
  const float* kbh = KBar + bh * 128; const float* vbh = VBar + bh * 128;

  for (int idx = tid; idx < 16384; idx += 256){
    int r = idx >> 7, c = idx & 127;
    float gg = G[(size_t)bh * 16384 + idx];
    float am = gkh[r] * (gvh[c] * gg + kbh[r] * bvh[c])
             + bkh[r] * (gvh[c] * vbh[c] + 32768.f * bvh[c]);
    sA[r * 129 + c] = am;
  }
  for (int idx = tid; idx < 4096; idx += 256){
    int r = idx >> 5, c = idx & 31;
    sS[r * 33 + c] = Wo[(size_t)hs * 16384 + r * 128 + eq * 32 + c];
  }
  __syncthreads();

  int r0 = (tid >> 4) * 8, e0 = (tid & 15) * 2;
  float t8[8][2] = {};
  for (int c = 0; c < 128; ++c){
    float wv0 = sS[c * 33 + e0], wv1 = sS[c * 33 + e0 + 1];
    #pragma unroll
    for (int i = 0; i < 8; ++i){
      float a = sA[(r0 + i) * 129 + c];
      t8[i][0] += a * wv0; t8[i][1] += a * wv1;
    }
  }
  __syncthreads();
  #pragma unroll
  for (int i = 0; i < 8; ++i){
    sS[(r0 + i) * 33 + e0]     = t8[i][0];
    sS[(r0 + i) * 33 + e0 + 1] = t8[i][1];
  }
  for (int idx = tid; idx < 16384; idx += 256){
    int r = idx >> 7, c = idx & 127;
    sA[r * 129 + c] = Wq[(size_t)r * 1024 + hs * 128 + c];
  }
  __syncthreads();

  float a8[8][2] = {};
  for (int d = 0; d < 128; ++d){
    float t0 = sS[d * 33 + e0], t1 = sS[d * 33 + e0 + 1];
    #pragma unroll
    for (int i = 0; i < 8; ++i){
      float w = sA[(r0 + i) * 129 + d];
      a8[i][0] += w * t0; a8[i][1] += w * t1;
    }
  }
  const float inv_n = 0.0009765625f; // 1/1024
  #pragma unroll
  for (int i = 0; i < 8; ++i){
    atomicAdd(W4 + (size_t)b * 16384 + (r0 + i) * 128 + eq * 32 + e0,     a8[i][0] * inv_n);
    atomicAdd(W4 + (size_t)b * 16384 + (r0 + i) * 128 + eq * 32 + e0 + 1, a8[i][1] * inv_n);
  }
  if (tid < 32){
    float s = 0.f;
    for (int d = 0; d < 128; ++d) s += Wq_b[hs * 128 + d] * sS[d * 33 + tid];
    if (hs == 0) s += Wo_b[eq * 32 + tid];
    atomicAdd(c4 + b * 128 + eq * 32 + tid, s * inv_n);
  }
}

// W4 (f32 [b][c][n]) -> W4T bf16 in B-fragment order
__global__ void kfold3(const float* __restrict__ W4, u16* __restrict__ W4T){
  int i = blockIdx.x * 256 + threadIdx.x;
  if (i >= 32768) return;
  int b = i >> 14, o = i & 16383;
  int e = o & 7, ln = (o >> 3) & 63, ks = (o >> 9) & 3, nt = (o >> 11) & 7;
  int c = ks * 32 + (ln >> 4) * 8 + e;
  int n = nt * 16 + (ln & 15);
  W4T[i] = (u16)f2bf(W4[(size_t)b * 16384 + c * 128 + n]);
}

// ---------------- out = x @ W4[b] + c4[b] ----------------
__global__ __launch_bounds__(256, 4) void kout(
    const u16* __restrict__ X, const u16* __restrict__ W4T,
    const float* __restrict__ c4, float* __restrict__ out)
{
  __shared__ char sW[32768];
  const int tid = threadIdx.x, wid = tid >> 6, lane = tid & 63, g = lane >> 4, l15 = lane & 15;
  const int blk = blockIdx.x, b = blk >> 8, ch = blk & 255;
  {
    const char* gw = (const char*)(W4T + (size_t)b * 16384);
    #pragma unroll
    for (int c = 0; c < 8; ++c){
      u32 o = (u32)(c * 4096 + tid * 16);
      gload16(gw + o, sW + o);
    }
  }
  const char* xr = (const char*)(X + ((size_t)b * L_TOT + ch * 128 + wid * 32 + l15) * 128) + g * 16;
  s16x8 af[2][4];
  #pragma unroll
  for (int mt = 0; mt < 2; ++mt)
    #pragma unroll
    for (int ks = 0; ks < 4; ++ks)
      af[mt][ks] = *(const s16x8*)(xr + mt * 4096 + ks * 64);
  asm volatile("s_waitcnt vmcnt(0)" ::: "memory");
  __builtin_amdgcn_s_barrier();

  f32x4 acc[2][8];
  #pragma unroll
  for (int mt = 0; mt < 2; ++mt)
    #pragma unroll
    for (int nt = 0; nt < 8; ++nt) acc[mt][nt] = f32x4{0.f, 0.f, 0.f, 0.f};

  const u32 wread = (u32)(lane * 16);
  #pragma unroll
  for (int ks = 0; ks < 4; ++ks)
    #pragma unroll
    for (int nt = 0; nt < 8; ++nt){
      s16x8 wf = *(const s16x8*)(sW + wread + (nt * 4 + ks) * 1024);
      acc[0][nt] = mfma16(af[0][ks], wf, acc[0][nt]);
      acc[1][nt] = mfma16(af[1][ks], wf, acc[1][nt]);
    }
  float* ob = out + ((size_t)b * L_TOT + ch * 128 + wid * 32) * 128;
  #pragma unroll
  for (int nt = 0; nt < 8; ++nt){
    float c4v = c4[b * 128 + nt * 16 + l15];
    #pragma unroll
    for (int mt = 0; mt < 2; ++mt)
      #pragma unroll
      for (int j = 0; j < 4; ++j)
        ob[(mt * 16 + g * 4 + j) * 128 + nt * 16 + l15] = acc[mt][nt][j] + c4v;
  }
}

extern "C" void kernel_launch(void* const* d_in, const int* in_sizes, int n_in,
                              void* d_out, int out_size, void* d_ws, size_t ws_size,
                              hipStream_t stream){
  const float* v    = (const float*)d_in[0];
  const float* Wq_w = (const float*)d_in[1];
  const float* Wq_b = (const float*)d_in[2];
  const float* Wk_w = (const float*)d_in[3];
  const float* Wk_b = (const float*)d_in[4];
  const float* Wv_w = (const float*)d_in[5];
  const float* Wv_b = (const float*)d_in[6];
  const float* Wo_w = (const float*)d_in[7];
  const float* Wo_b = (const float*)d_in[8];
  const float* lnk_g = (const float*)d_in[9];
  const float* lnk_b = (const float*)d_in[10];
  const float* lnv_g = (const float*)d_in[11];
  const float* lnv_b = (const float*)d_in[12];

  char* ws = (char*)d_ws;
  u16*   X    = (u16*)  (ws);              // 16777216 B
  u16*   WkF  = (u16*)  (ws + 16777216);   // 262144
  u16*   WvF  = (u16*)  (ws + 17039360);   // 262144
  float* G    = (float*)(ws + 17301504);   // 1048576
  float* KBar = (float*)(ws + 18350080);   // 8192
  float* VBar = (float*)(ws + 18358272);   // 8192
  float* W4   = (float*)(ws + 18366464);   // 131072
  float* c4   = (float*)(ws + 18497536);   // 1024
  u16*   W4T  = (u16*)  (ws + 18498560);   // 65536

  hipMemsetAsync(ws + 17301504, 0, 1197056, stream); // G, KBar, VBar, W4, c4

  hipLaunchKernelGGL(kprep, dim3(2048), dim3(256), 0, stream, v, Wk_w, Wv_w, X, WkF, WvF);

  hipLaunchKernelGGL(kattn, dim3(256), dim3(256), 0, stream,
                     X, WkF, WvF, Wk_b, Wv_b, G, KBar, VBar);

  (void)hipFuncSetAttribute((const void*)kfold,
                            hipFuncAttributeMaxDynamicSharedMemorySize, 83968);
  hipLaunchKernelGGL(kfold, dim3(64), dim3(256), 83968, stream,
                     G, KBar, VBar, lnk_g, lnk_b, lnv_g, lnv_b,
                     Wo_w, Wq_w, Wq_b, Wo_b, W4, c4);
  hipLaunchKernelGGL(kfold3, dim3(128), dim3(256), 0, stream, W4, W4T);

  hipLaunchKernelGGL(kout, dim3(512), dim3(256), 0, stream, X, W4T, c4, (float*)d_out);
}

// Round 5
// 155.606 us; speedup vs baseline: 3.7371x; 3.7371x over previous
//
#include <hip/hip_runtime.h>
#include <stdint.h>

typedef unsigned short u16;
typedef unsigned int u32;
typedef __attribute__((ext_vector_type(8))) short s16x8;
typedef __attribute__((ext_vector_type(8))) __bf16 bf16x8;
typedef __attribute__((ext_vector_type(4))) float f32x4;
typedef __attribute__((ext_vector_type(4))) u32 u32x4;
typedef __attribute__((ext_vector_type(4))) u16 u16x4;

#define L_TOT 32768
#define NCH 16   // 128-row chunks per kattn block

__device__ __forceinline__ u32 f2bf(float f){
  u32 u = __builtin_bit_cast(u32, f);
  return (u + 0x7FFFu + ((u >> 16) & 1u)) >> 16;
}

__device__ __forceinline__ f32x4 mfma16(s16x8 a, s16x8 b, f32x4 c){
  return __builtin_amdgcn_mfma_f32_16x16x32_bf16(
      __builtin_bit_cast(bf16x8, a), __builtin_bit_cast(bf16x8, b), c, 0, 0, 0);
}

__device__ __forceinline__ void gload16(const void* g, void* l){
  __builtin_amdgcn_global_load_lds(
      (const __attribute__((address_space(1))) void*)g,
      (__attribute__((address_space(3))) void*)l, 16, 0, 0);
}

__device__ __forceinline__ u32 cvtpk(float lo, float hi){
  u32 r;
  asm("v_cvt_pk_bf16_f32 %0, %1, %2" : "=v"(r) : "v"(lo), "v"(hi));
  return r;
}

// sum across the 16 lanes of each row-group, VALU-only
__device__ __forceinline__ float dpp_reduce16(float x){
  float y;
  asm("v_add_f32_dpp %0, %1, %1 row_ror:8 row_mask:0xf bank_mask:0xf"
      : "=&v"(y) : "v"(x));
  asm("v_add_f32_dpp %0, %1, %1 row_ror:4 row_mask:0xf bank_mask:0xf"
      : "=&v"(x) : "v"(y));
  asm("v_add_f32_dpp %0, %1, %1 quad_perm:[2,3,0,1] row_mask:0xf bank_mask:0xf"
      : "=&v"(y) : "v"(x));
  asm("v_add_f32_dpp %0, %1, %1 quad_perm:[1,0,3,2] row_mask:0xf bank_mask:0xf"
      : "=&v"(x) : "v"(y));
  return x;
}

// C-frag of two row-tiles -> A/B-frag for the G MFMA (validated in round 4)
__device__ __forceinline__ s16x8 build_frag(f32x4 t0, f32x4 t1){
  u32 p0 = cvtpk(t0.x, t0.y);
  u32 p1 = cvtpk(t0.z, t0.w);
  u32 p2 = cvtpk(t1.x, t1.y);
  u32 p3 = cvtpk(t1.z, t1.w);
  asm("v_permlane32_swap_b32 %0, %1" : "+v"(p0), "+v"(p2));
  asm("v_permlane16_swap_b32 %0, %1" : "+v"(p0), "+v"(p2));
  asm("v_permlane32_swap_b32 %0, %1" : "+v"(p1), "+v"(p3));
  asm("v_permlane16_swap_b32 %0, %1" : "+v"(p1), "+v"(p3));
  u32x4 r; r.x = p0; r.y = p1; r.z = p2; r.w = p3;
  return __builtin_bit_cast(s16x8, r);
}

// center+scale (LayerNorm without gamma/beta): acc <- rstd*(acc+bias-mean)
__device__ __forceinline__ void ln_center(f32x4 (&acc)[2][8], const float (&br)[8]){
  #pragma unroll
  for (int mt = 0; mt < 2; ++mt){
    f32x4 sum = {0.f,0.f,0.f,0.f}, sq = {0.f,0.f,0.f,0.f};
    #pragma unroll
    for (int nt = 0; nt < 8; ++nt){
      f32x4 t = acc[mt][nt] + f32x4{br[nt], br[nt], br[nt], br[nt]};
      acc[mt][nt] = t; sum += t; sq += t * t;
    }
    f32x4 s4, ns4;
    #pragma unroll
    for (int j = 0; j < 4; ++j){
      float ss = dpp_reduce16(sum[j]);
      float qq = dpp_reduce16(sq[j]);
      float mean = ss * 0.0078125f;
      float var  = qq * 0.0078125f - mean * mean;
      float rstd = rsqrtf(var + 1e-5f);
      s4[j] = rstd; ns4[j] = -mean * rstd;
    }
    #pragma unroll
    for (int nt = 0; nt < 8; ++nt) acc[mt][nt] = acc[mt][nt] * s4 + ns4;
  }
}

// ------- prep: v -> bf16 X; Wk/Wv -> bf16 in MFMA B-fragment order -------
__global__ void kprep(const float* __restrict__ v, const float* __restrict__ Wk,
                      const float* __restrict__ Wv, u16* __restrict__ X,
                      u16* __restrict__ WkF, u16* __restrict__ WvF){
  int tid = blockIdx.x * blockDim.x + threadIdx.x;
  int stride = gridDim.x * blockDim.x;
  for (int i = tid; i < 2097152; i += stride){
    float4 f = *((const float4*)v + i);
    u16x4 o; o.x = (u16)f2bf(f.x); o.y = (u16)f2bf(f.y); o.z = (u16)f2bf(f.z); o.w = (u16)f2bf(f.w);
    *((u16x4*)X + i) = o;
  }
  for (int i = tid; i < 131072; i += stride){
    int e = i & 7, ln = (i >> 3) & 63, ks = (i >> 9) & 3, nt = (i >> 11) & 7, h = i >> 14;
    int c = ks * 32 + (ln >> 4) * 8 + e;
    int n = nt * 16 + (ln & 15);
    int src = c * 1024 + h * 128 + n;
    WkF[i] = (u16)f2bf(Wk[src]);
    WvF[i] = (u16)f2bf(Wv[src]);
  }
}

// --------- fused K/V projection + centered-scale + G += K''^T V'' ---------
// 512 thr: waves 0-3 K-proj, 4-7 V-proj (32 rows each). Pipelined span:
// [G-reads(i) | proj-MFMA(i+1) | G-MFMA(i)] LN(i+1) barA store(i+1) barB.
__global__ __launch_bounds__(512, 2) void kattn(
    const u16* __restrict__ X, const u16* __restrict__ WkF, const u16* __restrict__ WvF,
    const float* __restrict__ bk, const float* __restrict__ bv,
    float* __restrict__ G, float* __restrict__ KBar, float* __restrict__ VBar)
{
  extern __shared__ char smem[];
  char* sWK = smem;            // 32 KiB K weight frags
  char* sWV = smem + 32768;    // 32 KiB V weight frags
  char* sKF = smem + 65536;    // 32 KiB K'' frags for current chunk
  char* sVF = smem + 98304;    // 32 KiB V'' frags

  const int tid = threadIdx.x;
  const int wid = tid >> 6, lane = tid & 63, g = lane >> 4, l15 = lane & 15;
  const int bh = blockIdx.x >> 4, lgrp = blockIdx.x & 15;
  const int b = bh >> 3, h = bh & 7;
  const bool isK = (wid < 4);
  const int w4 = wid & 3;
  const int dkt = (wid >> 2) * 4;

  { // stage weight frags (linear, already fragment-ordered in global)
    const char* gwk = (const char*)(WkF + h * 16384);
    const char* gwv = (const char*)(WvF + h * 16384);
    #pragma unroll
    for (int c = 0; c < 4; ++c){
      u32 o = (u32)(c * 8192 + tid * 16);
      gload16(gwk + o, sWK + o);
      gload16(gwv + o, sWV + o);
    }
  }
  const float* bias = isK ? bk : bv;
  float br[8];
  #pragma unroll
  for (int nt = 0; nt < 8; ++nt) br[nt] = bias[h * 128 + nt * 16 + l15];

  const char* sW = isK ? sWK : sWV;
  char* stf = (isK ? sKF : sVF) + w4 * 1024 + lane * 16;
  const char* kfb = sKF + lane * 16;
  const char* vfb = sVF + lane * 16;
  const u16* Xb = X + (size_t)b * (L_TOT * 128);
  const char* xlane = (const char*)Xb
      + ((size_t)(lgrp * (NCH * 128)) + w4 * 32 + l15) * 256 + g * 16;
  const u32 wread = (u32)(lane * 16);

  f32x4 am[4][2];
  #pragma unroll
  for (int t = 0; t < 4; ++t)
    #pragma unroll
    for (int u2 = 0; u2 < 2; ++u2) am[t][u2] = f32x4{0.f,0.f,0.f,0.f};
  float kbv[8] = {0,0,0,0,0,0,0,0};
  s16x8 afA[2][4], afB[2][4], cf[8];

#define PREF(dst, it) { \
  const char* p_ = xlane + (size_t)(it) * 32768; \
  _Pragma("unroll") for (int mt_ = 0; mt_ < 2; ++mt_) \
  _Pragma("unroll") for (int ks_ = 0; ks_ < 4; ++ks_) \
    dst[mt_][ks_] = *(const s16x8*)(p_ + mt_ * 4096 + ks_ * 64); }

#define LNBUILD(ACC) { \
    ln_center(ACC, br); \
    _Pragma("unroll") for (int nt = 0; nt < 8; ++nt){ \
      f32x4 s_ = ACC[0][nt] + ACC[1][nt]; \
      kbv[nt] += (s_.x + s_.y) + (s_.z + s_.w); \
      cf[nt] = build_frag(ACC[0][nt], ACC[1][nt]); \
    } }

#define STORECF() { \
    _Pragma("unroll") for (int nt = 0; nt < 8; ++nt) \
      *(s16x8*)(stf + nt * 4096) = cf[nt]; \
    asm volatile("s_waitcnt lgkmcnt(0)" ::: "memory"); \
    __builtin_amdgcn_sched_barrier(0); }

#define BAR() { asm volatile("" ::: "memory"); \
    __builtin_amdgcn_s_barrier(); \
    asm volatile("" ::: "memory"); }

// One pipeline iteration: G(i) from LDS frags + (optionally) proj(i+1)
#define SPAN(FCUR, FPRE, prefit, DO_NEXT) { \
    f32x4 acc[2][8]; \
    if (DO_NEXT){ \
      _Pragma("unroll") for (int mt = 0; mt < 2; ++mt) \
        _Pragma("unroll") for (int nt = 0; nt < 8; ++nt) acc[mt][nt] = f32x4{0.f,0.f,0.f,0.f}; \
    } \
    __builtin_amdgcn_s_setprio(1); \
    _Pragma("unroll") for (int ks2 = 0; ks2 < 4; ++ks2){ \
      s16x8 a2[4], b2[2]; \
      _Pragma("unroll") for (int t = 0; t < 4; ++t) \
        a2[t] = *(const s16x8*)(kfb + (dkt + t) * 4096 + ks2 * 1024); \
      _Pragma("unroll") for (int u2 = 0; u2 < 2; ++u2) \
        b2[u2] = *(const s16x8*)(vfb + (w4 * 2 + u2) * 4096 + ks2 * 1024); \
      if (DO_NEXT){ \
        _Pragma("unroll") for (int nt = 0; nt < 8; ++nt){ \
          s16x8 wf = *(const s16x8*)(sW + wread + (nt * 4 + ks2) * 1024); \
          acc[0][nt] = mfma16(FCUR[0][ks2], wf, acc[0][nt]); \
          acc[1][nt] = mfma16(FCUR[1][ks2], wf, acc[1][nt]); \
        } \
      } \
      _Pragma("unroll") for (int t = 0; t < 4; ++t) \
        _Pragma("unroll") for (int u2 = 0; u2 < 2; ++u2) \
          am[t][u2] = mfma16(a2[t], b2[u2], am[t][u2]); \
    } \
    __builtin_amdgcn_s_setprio(0); \
    if (DO_NEXT){ \
      PREF(FPRE, prefit); \
      LNBUILD(acc); \
    } \
    BAR(); \
    if (DO_NEXT){ STORECF(); } \
    BAR(); }

  // ---- prologue: chunk 0 projection ----
  PREF(afA, 0);
  PREF(afB, 1);
  asm volatile("s_waitcnt vmcnt(0)" ::: "memory");
  BAR();
  {
    f32x4 acc[2][8];
    #pragma unroll
    for (int mt = 0; mt < 2; ++mt)
      #pragma unroll
      for (int nt = 0; nt < 8; ++nt) acc[mt][nt] = f32x4{0.f,0.f,0.f,0.f};
    #pragma unroll
    for (int ks = 0; ks < 4; ++ks)
      #pragma unroll
      for (int nt = 0; nt < 8; ++nt){
        s16x8 wf = *(const s16x8*)(sW + wread + (nt * 4 + ks) * 1024);
        acc[0][nt] = mfma16(afA[0][ks], wf, acc[0][nt]);
        acc[1][nt] = mfma16(afA[1][ks], wf, acc[1][nt]);
      }
    LNBUILD(acc);
  }
  STORECF();
  BAR();

  // ---- main pipeline: iter i does G(i) + proj(i+1) ----
  #pragma unroll 1
  for (int i = 0; i < NCH; i += 2){
    SPAN(afB, afA, (i + 2 < NCH) ? (i + 2) : 0, true);              // i even
    if (i + 1 < NCH - 1){ SPAN(afA, afB, (i + 3 < NCH) ? (i + 3) : 0, true); }
    else                { SPAN(afA, afB, 0, false); }               // last: G only
  }
#undef SPAN
#undef BAR
#undef STORECF
#undef LNBUILD
#undef PREF

  float* Gbh = G + (size_t)bh * 16384;
  #pragma unroll
  for (int t = 0; t < 4; ++t)
    #pragma unroll
    for (int u2 = 0; u2 < 2; ++u2)
      #pragma unroll
      for (int j = 0; j < 4; ++j){
        int dk = (wid >> 2) * 64 + t * 16 + g * 4 + j;
        int dv = w4 * 32 + u2 * 16 + l15;
        atomicAdd(Gbh + dk * 128 + dv, am[t][u2][j]);
      }
  float* dstB = (isK ? KBar : VBar) + bh * 128;
  #pragma unroll
  for (int nt = 0; nt < 8; ++nt){
    float s = kbv[nt];
    s += __shfl_xor(s, 16); s += __shfl_xor(s, 32);
    if (g == 0) atomicAdd(dstB + nt * 16 + l15, s);
  }
}

// --------- fold: AM = corrections(G); tmp = AM@Wo ; W4F += frag(Wq@tmp)/n ---------
__global__ __launch_bounds__(256) void kfold(
    const float* __restrict__ G, const float* __restrict__ KBar, const float* __restrict__ VBar,
    const float* __restrict__ gk, const float* __restrict__ bbk,
    const float* __restrict__ gv, const float* __restrict__ bbv,
    const float* __restrict__ Wo, const float* __restrict__ Wq,
    const float* __restrict__ Wq_b, const float* __restrict__ Wo_b,
    float* __restrict__ W4F, float* __restrict__ c4)
{
  extern __shared__ float fsm[];
  float* sA = fsm;               // [128][129]
  float* sS = fsm + 128 * 129;   // [128][33]
  int blk = blockIdx.x;
  int bh = blk >> 2, eq = blk & 3;
  int b = bh >> 3, hs = bh & 7;
  int tid = threadIdx.x;

  const float* gkh = gk + hs * 128; const float* bkh = bbk + hs * 128;
  const float* gvh = gv + hs * 128; const float* bvh = bbv + hs * 128;
  const float* kbh = KBar + bh * 128; const float* vbh = VBar + bh * 128;

  for (int idx = tid; idx < 16384; idx += 256){
    int r = idx >> 7, c = idx & 127;
    float gg = G[(size_t)bh * 16384 + idx];
    float amv = gkh[r] * (gvh[c] * gg + kbh[r] * bvh[c])
              + bkh[r] * (gvh[c] * vbh[c] + 32768.f * bvh[c]);
    sA[r * 129 + c] = amv;
  }
  for (int idx = tid; idx < 4096; idx += 256){
    int r = idx >> 5, c = idx & 31;
    sS[r * 33 + c] = Wo[(size_t)hs * 16384 + r * 128 + eq * 32 + c];
  }
  __syncthreads();

  int r0 = (tid >> 4) * 8, e0 = (tid & 15) * 2;
  float t8[8][2] = {};
  for (int c = 0; c < 128; ++c){
    float wv0 = sS[c * 33 + e0], wv1 = sS[c * 33 + e0 + 1];
    #pragma unroll
    for (int i = 0; i < 8; ++i){
      float a = sA[(r0 + i) * 129 + c];
      t8[i][0] += a * wv0; t8[i][1] += a * wv1;
    }
  }
  __syncthreads();
  #pragma unroll
  for (int i = 0; i < 8; ++i){
    sS[(r0 + i) * 33 + e0]     = t8[i][0];
    sS[(r0 + i) * 33 + e0 + 1] = t8[i][1];
  }
  for (int idx = tid; idx < 16384; idx += 256){
    int r = idx >> 7, c = idx & 127;
    sA[r * 129 + c] = Wq[(size_t)r * 1024 + hs * 128 + c];
  }
  __syncthreads();

  float a8[8][2] = {};
  for (int d = 0; d < 128; ++d){
    float t0 = sS[d * 33 + e0], t1 = sS[d * 33 + e0 + 1];
    #pragma unroll
    for (int i = 0; i < 8; ++i){
      float w = sA[(r0 + i) * 129 + d];
      a8[i][0] += w * t0; a8[i][1] += w * t1;
    }
  }
  const float inv_n = 0.0009765625f; // 1/1024
  // atomicAdd directly into bf16-fragment-ordered f32 buffer
  #pragma unroll
  for (int i = 0; i < 8; ++i)
    #pragma unroll
    for (int j = 0; j < 2; ++j){
      int cc = r0 + i, nn = eq * 32 + e0 + j;
      int o = ((nn >> 4) * 4 + (cc >> 5)) * 512 + ((cc >> 3) & 3) * 128
            + (nn & 15) * 8 + (cc & 7);
      atomicAdd(W4F + (size_t)b * 16384 + o, a8[i][j] * inv_n);
    }
  if (tid < 32){
    float s = 0.f;
    for (int d = 0; d < 128; ++d) s += Wq_b[hs * 128 + d] * sS[d * 33 + tid];
    if (hs == 0) s += Wo_b[eq * 32 + tid];
    atomicAdd(c4 + b * 128 + eq * 32 + tid, s * inv_n);
  }
}

// ---------------- out = x @ W4[b] + c4[b] ----------------
__global__ __launch_bounds__(256, 4) void kout(
    const u16* __restrict__ X, const float* __restrict__ W4F,
    const float* __restrict__ c4, float* __restrict__ out)
{
  __shared__ char sW[32768];
  const int tid = threadIdx.x, wid = tid >> 6, lane = tid & 63, g = lane >> 4, l15 = lane & 15;
  const int blk = blockIdx.x, b = blk >> 8, ch = blk & 255;
  { // stage W4F f32 -> bf16 frags (coalesced float4 + cvt_pk, linear ds_write)
    const float* w4b = W4F + (size_t)b * 16384;
    #pragma unroll
    for (int it2 = 0; it2 < 16; ++it2){
      int idx = it2 * 1024 + tid * 4;
      float4 f = *(const float4*)(w4b + idx);
      uint2 w; w.x = cvtpk(f.x, f.y); w.y = cvtpk(f.z, f.w);
      *(uint2*)(sW + idx * 2) = w;
    }
  }
  const char* xr = (const char*)(X + ((size_t)b * L_TOT + ch * 128 + wid * 32 + l15) * 128) + g * 16;
  s16x8 af[2][4];
  #pragma unroll
  for (int mt = 0; mt < 2; ++mt)
    #pragma unroll
    for (int ks = 0; ks < 4; ++ks)
      af[mt][ks] = *(const s16x8*)(xr + mt * 4096 + ks * 64);
  __syncthreads();

  f32x4 acc[2][8];
  #pragma unroll
  for (int mt = 0; mt < 2; ++mt)
    #pragma unroll
    for (int nt = 0; nt < 8; ++nt) acc[mt][nt] = f32x4{0.f, 0.f, 0.f, 0.f};

  const u32 wread = (u32)(lane * 16);
  #pragma unroll
  for (int ks = 0; ks < 4; ++ks)
    #pragma unroll
    for (int nt = 0; nt < 8; ++nt){
      s16x8 wf = *(const s16x8*)(sW + wread + (nt * 4 + ks) * 1024);
      acc[0][nt] = mfma16(af[0][ks], wf, acc[0][nt]);
      acc[1][nt] = mfma16(af[1][ks], wf, acc[1][nt]);
    }
  float* ob = out + ((size_t)b * L_TOT + ch * 128 + wid * 32) * 128;
  #pragma unroll
  for (int nt = 0; nt < 8; ++nt){
    float c4v = c4[b * 128 + nt * 16 + l15];
    #pragma unroll
    for (int mt = 0; mt < 2; ++mt)
      #pragma unroll
      for (int j = 0; j < 4; ++j)
        ob[(mt * 16 + g * 4 + j) * 128 + nt * 16 + l15] = acc[mt][nt][j] + c4v;
  }
}

extern "C" void kernel_launch(void* const* d_in, const int* in_sizes, int n_in,
                              void* d_out, int out_size, void* d_ws, size_t ws_size,
                              hipStream_t stream){
  const float* v    = (const float*)d_in[0];
  const float* Wq_w = (const float*)d_in[1];
  const float* Wq_b = (const float*)d_in[2];
  const float* Wk_w = (const float*)d_in[3];
  const float* Wk_b = (const float*)d_in[4];
  const float* Wv_w = (const float*)d_in[5];
  const float* Wv_b = (const float*)d_in[6];
  const float* Wo_w = (const float*)d_in[7];
  const float* Wo_b = (const float*)d_in[8];
  const float* lnk_g = (const float*)d_in[9];
  const float* lnk_b = (const float*)d_in[10];
  const float* lnv_g = (const float*)d_in[11];
  const float* lnv_b = (const float*)d_in[12];

  char* ws = (char*)d_ws;
  u16*   X    = (u16*)  (ws);              // 16777216 B
  u16*   WkF  = (u16*)  (ws + 16777216);   // 262144
  u16*   WvF  = (u16*)  (ws + 17039360);   // 262144
  float* G    = (float*)(ws + 17301504);   // 1048576
  float* KBar = (float*)(ws + 18350080);   // 8192
  float* VBar = (float*)(ws + 18358272);   // 8192
  float* W4F  = (float*)(ws + 18366464);   // 131072
  float* c4   = (float*)(ws + 18497536);   // 1024

  hipMemsetAsync(ws + 17301504, 0, 1197056, stream); // G, KBar, VBar, W4F, c4

  hipLaunchKernelGGL(kprep, dim3(2048), dim3(256), 0, stream, v, Wk_w, Wv_w, X, WkF, WvF);

  (void)hipFuncSetAttribute((const void*)kattn,
                            hipFuncAttributeMaxDynamicSharedMemorySize, 131072);
  hipLaunchKernelGGL(kattn, dim3(256), dim3(512), 131072, stream,
                     X, WkF, WvF, Wk_b, Wv_b, G, KBar, VBar);

  (void)hipFuncSetAttribute((const void*)kfold,
                            hipFuncAttributeMaxDynamicSharedMemorySize, 83968);
  hipLaunchKernelGGL(kfold, dim3(64), dim3(256), 83968, stream,
                     G, KBar, VBar, lnk_g, lnk_b, lnv_g, lnv_b,
                     Wo_w, Wq_w, Wq_b, Wo_b, W4F, c4);

  hipLaunchKernelGGL(kout, dim3(512), dim3(256), 0, stream, X, W4F, c4, (float*)d_out);
}